// Round 1
// baseline (150.862 us; speedup 1.0000x reference)
//
#include <hip/hip_runtime.h>
#include <hip/hip_bf16.h>

#define DIM 1024
#define SEQ 4096
#define NB 4
#define MROWS (NB * SEQ)   // 16384
#define NC 16              // chunks per sequence
#define CL (SEQ / NC)      // 256 L-positions per chunk

typedef __attribute__((ext_vector_type(8))) short bf16x8;
typedef __attribute__((ext_vector_type(4))) float f32x4;

static __device__ __forceinline__ unsigned short f2bf(float f) {
    union { float f; unsigned u; } v; v.f = f;
    unsigned r = v.u + 0x7FFF + ((v.u >> 16) & 1);
    return (unsigned short)(r >> 16);
}

static __device__ __forceinline__ void gload_lds16(const void* g, void* l) {
    __builtin_amdgcn_global_load_lds((const __attribute__((address_space(1))) void*)g,
                                     (__attribute__((address_space(3))) void*)l, 16, 0, 0);
}

// ---- convert x and W fp32 -> bf16 (packed ushort), 4 elems/thread ----
__global__ void convert_kernel(const float* __restrict__ x, const float* __restrict__ W,
                               unsigned short* __restrict__ xb, unsigned short* __restrict__ wb) {
    const long long NX4 = (long long)MROWS * DIM / 4;   // 4,194,304
    const long long NW4 = (long long)DIM * DIM / 4;     // 262,144
    long long t = (long long)blockIdx.x * blockDim.x + threadIdx.x;
    if (t < NX4) {
        float4 v = ((const float4*)x)[t];
        ushort4 o;
        o.x = f2bf(v.x); o.y = f2bf(v.y); o.z = f2bf(v.z); o.w = f2bf(v.w);
        ((ushort4*)xb)[t] = o;
    } else if (t < NX4 + NW4) {
        long long u = t - NX4;
        float4 v = ((const float4*)W)[u];
        ushort4 o;
        o.x = f2bf(v.x); o.y = f2bf(v.y); o.z = f2bf(v.z); o.w = f2bf(v.w);
        ((ushort4*)wb)[u] = o;
    }
}

// ---- GEMM: C[m][n] = sum_k A[m][k]*B[n][k] + bias[n] ----
// A = xb [MROWS][1024], B = Wb [1024][1024] (both K-contiguous -> B^T gemm)
__global__ __launch_bounds__(256) void gemm_kernel(const unsigned short* __restrict__ A,
                                                   const unsigned short* __restrict__ Bm,
                                                   const float* __restrict__ bias,
                                                   float* __restrict__ C) {
    __shared__ unsigned short As[128 * 64];
    __shared__ unsigned short Bs[128 * 64];
    const int K = DIM;
    const int tid  = threadIdx.x;
    const int lane = tid & 63;
    const int w    = tid >> 6;          // wave 0..3
    const int m0 = blockIdx.x * 128;
    const int n0 = blockIdx.y * 128;

    f32x4 acc[4][4];
#pragma unroll
    for (int m = 0; m < 4; ++m)
#pragma unroll
        for (int n = 0; n < 4; ++n)
            acc[m][n] = (f32x4){0.f, 0.f, 0.f, 0.f};

    const int wr = (w >> 1) * 64;   // wave row offset in tile
    const int wc = (w & 1) * 64;    // wave col offset in tile
    const int rl = lane & 15;
    const int rh = lane >> 4;

    for (int k0 = 0; k0 < K; k0 += 64) {
        // stage 128x64 bf16 of A and B into LDS (linear layout, 16B/lane)
#pragma unroll
        for (int r = 0; r < 4; ++r) {
            int idx8 = (r * 4 + w) * 64 + lane;       // 0..1023, each covers 8 bf16
            int row  = idx8 >> 3;                     // 0..127
            int col  = (idx8 & 7) * 8;                // 0..56
            gload_lds16(A + (size_t)(m0 + row) * K + k0 + col, As + idx8 * 8);
            gload_lds16(Bm + (size_t)(n0 + row) * K + k0 + col, Bs + idx8 * 8);
        }
        __syncthreads();
#pragma unroll
        for (int kk = 0; kk < 2; ++kk) {
            const int kof = kk * 32 + rh * 8;
            bf16x8 af[4], bfr[4];
#pragma unroll
            for (int m = 0; m < 4; ++m)
                af[m] = *(const bf16x8*)(As + (wr + m * 16 + rl) * 64 + kof);
#pragma unroll
            for (int n = 0; n < 4; ++n)
                bfr[n] = *(const bf16x8*)(Bs + (wc + n * 16 + rl) * 64 + kof);
#pragma unroll
            for (int m = 0; m < 4; ++m)
#pragma unroll
                for (int n = 0; n < 4; ++n)
                    acc[m][n] = __builtin_amdgcn_mfma_f32_16x16x32_bf16(af[m], bfr[n], acc[m][n], 0, 0, 0);
        }
        __syncthreads();
    }

    // epilogue: C/D layout col = lane&15, row = (lane>>4)*4 + reg
#pragma unroll
    for (int m = 0; m < 4; ++m) {
#pragma unroll
        for (int n = 0; n < 4; ++n) {
            int gcol = n0 + wc + n * 16 + rl;
            float bv = bias[gcol];
#pragma unroll
            for (int j = 0; j < 4; ++j) {
                int grow = m0 + wr + m * 16 + rh * 4 + j;
                C[(size_t)grow * DIM + gcol] = acc[m][n][j] + bv;
            }
        }
    }
}

// ---- pass A: per-chunk sums of v*cos, v*sin ----
__global__ void passA_kernel(const float* __restrict__ val, const float* __restrict__ ph,
                             float* __restrict__ pr, float* __restrict__ pi) {
    int e  = blockIdx.x * 256 + threadIdx.x;
    int c  = blockIdx.y;
    int bb = blockIdx.z;
    const float* v = val + ((size_t)bb * SEQ + (size_t)c * CL) * DIM + e;
    const float* p = ph + (size_t)c * CL * DIM + e;
    float sr = 0.f, si = 0.f;
    for (int l = 0; l < CL; ++l) {
        float vv = v[(size_t)l * DIM];
        float pp = p[(size_t)l * DIM];
        float s, cn;
        __sincosf(pp, &s, &cn);
        sr += vv * cn;
        si += vv * s;
    }
    size_t idx = ((size_t)bb * NC + c) * DIM + e;
    pr[idx] = sr;
    pi[idx] = si;
}

// ---- pass B: exclusive scan of chunk partials over c ----
__global__ void passB_kernel(float* __restrict__ pr, float* __restrict__ pi) {
    int t = blockIdx.x * 256 + threadIdx.x;   // 0..4095
    int bb = t >> 10;
    int e  = t & 1023;
    float r = 0.f, im = 0.f;
    for (int c = 0; c < NC; ++c) {
        size_t idx = ((size_t)bb * NC + c) * DIM + e;
        float tr = pr[idx], ti = pi[idx];
        pr[idx] = r; pi[idx] = im;
        r += tr; im += ti;
    }
}

// ---- pass C: in-chunk running cumsum + retrieval + norm, in-place on d_out ----
__global__ void passC_kernel(float* __restrict__ out, const float* __restrict__ ph,
                             const float* __restrict__ pr, const float* __restrict__ pi) {
    int e  = blockIdx.x * 256 + threadIdx.x;
    int c  = blockIdx.y;
    int bb = blockIdx.z;
    size_t base = ((size_t)bb * SEQ + (size_t)c * CL) * DIM + e;
    const float* p = ph + (size_t)c * CL * DIM + e;
    size_t pidx = ((size_t)bb * NC + c) * DIM + e;
    float ar = pr[pidx];
    float ai = pi[pidx];
    const int l0 = c * CL;
    for (int l = 0; l < CL; ++l) {
        float vv = out[base + (size_t)l * DIM];
        float pp = p[(size_t)l * DIM];
        float s, cn;
        __sincosf(pp, &s, &cn);
        ar += vv * cn;
        ai += vv * s;
        out[base + (size_t)l * DIM] = (ar * cn + ai * s) * rsqrtf((float)(l0 + l + 1));
    }
}

extern "C" void kernel_launch(void* const* d_in, const int* in_sizes, int n_in,
                              void* d_out, int out_size, void* d_ws, size_t ws_size,
                              hipStream_t stream) {
    const float* x  = (const float*)d_in[0];
    const float* ph = (const float*)d_in[1];   // base_phases [8192][1024]; use first 4096 rows
    const float* W  = (const float*)d_in[2];
    const float* b  = (const float*)d_in[3];
    float* out = (float*)d_out;

    // workspace layout
    unsigned short* xb = (unsigned short*)d_ws;                            // 32 MB
    unsigned short* wb = xb + (size_t)MROWS * DIM;                         // 2 MB
    float* pr = (float*)(wb + (size_t)DIM * DIM);                          // 256 KB
    float* pi = pr + (size_t)NB * NC * DIM;                                // 256 KB

    // 1) convert to bf16
    {
        long long total4 = (long long)MROWS * DIM / 4 + (long long)DIM * DIM / 4;
        int blocks = (int)((total4 + 255) / 256);
        convert_kernel<<<blocks, 256, 0, stream>>>(x, W, xb, wb);
    }
    // 2) GEMM -> value into d_out
    {
        dim3 grid(MROWS / 128, DIM / 128);
        gemm_kernel<<<grid, 256, 0, stream>>>(xb, wb, b, out);
    }
    // 3) chunk partial sums
    {
        dim3 grid(DIM / 256, NC, NB);
        passA_kernel<<<grid, 256, 0, stream>>>(out, ph, pr, pi);
    }
    // 4) scan partials
    passB_kernel<<<16, 256, 0, stream>>>(pr, pi);
    // 5) final cumsum + retrieve + norm (in place on d_out)
    {
        dim3 grid(DIM / 256, NC, NB);
        passC_kernel<<<grid, 256, 0, stream>>>(out, ph, pr, pi);
    }
}

// Round 2
// 112.419 us; speedup vs baseline: 1.3420x; 1.3420x over previous
//
#include <hip/hip_runtime.h>
#include <hip/hip_bf16.h>

#define DIM 1024
#define SEQ 4096
#define NB 4
#define MROWS (NB * SEQ)   // 16384
#define NC 64              // chunks per sequence
#define CL (SEQ / NC)      // 64 L-positions per chunk

typedef __attribute__((ext_vector_type(8))) short bf16x8;
typedef __attribute__((ext_vector_type(4))) float f32x4;

static __device__ __forceinline__ unsigned short f2bf(float f) {
    union { float f; unsigned u; } v; v.f = f;
    unsigned r = v.u + 0x7FFF + ((v.u >> 16) & 1);
    return (unsigned short)(r >> 16);
}

static __device__ __forceinline__ float bf2f(unsigned short h) {
    union { unsigned u; float f; } v; v.u = ((unsigned)h) << 16;
    return v.f;
}

static __device__ __forceinline__ void gload_lds16(const void* g, void* l) {
    __builtin_amdgcn_global_load_lds((const __attribute__((address_space(1))) void*)g,
                                     (__attribute__((address_space(3))) void*)l, 16, 0, 0);
}

// ---- convert x and W fp32 -> bf16 (packed ushort), 4 elems/thread ----
// destinations live in d_out (scratch until passC overwrites it)
__global__ void convert_kernel(const float* __restrict__ x, const float* __restrict__ W,
                               unsigned short* __restrict__ xb, unsigned short* __restrict__ wb) {
    const long long NX4 = (long long)MROWS * DIM / 4;   // 4,194,304
    const long long NW4 = (long long)DIM * DIM / 4;     // 262,144
    long long t = (long long)blockIdx.x * blockDim.x + threadIdx.x;
    if (t < NX4) {
        float4 v = ((const float4*)x)[t];
        ushort4 o;
        o.x = f2bf(v.x); o.y = f2bf(v.y); o.z = f2bf(v.z); o.w = f2bf(v.w);
        ((ushort4*)xb)[t] = o;
    } else if (t < NX4 + NW4) {
        long long u = t - NX4;
        float4 v = ((const float4*)W)[u];
        ushort4 o;
        o.x = f2bf(v.x); o.y = f2bf(v.y); o.z = f2bf(v.z); o.w = f2bf(v.w);
        ((ushort4*)wb)[u] = o;
    }
}

// ---- GEMM: V[m][n] = bf16( sum_k A[m][k]*B[n][k] + bias[n] ) ----
__global__ __launch_bounds__(256) void gemm_kernel(const unsigned short* __restrict__ A,
                                                   const unsigned short* __restrict__ Bm,
                                                   const float* __restrict__ bias,
                                                   unsigned short* __restrict__ V) {
    __shared__ unsigned short As[128 * 64];
    __shared__ unsigned short Bs[128 * 64];
    const int K = DIM;
    const int tid  = threadIdx.x;
    const int lane = tid & 63;
    const int w    = tid >> 6;          // wave 0..3
    const int m0 = blockIdx.x * 128;
    const int n0 = blockIdx.y * 128;

    f32x4 acc[4][4];
#pragma unroll
    for (int m = 0; m < 4; ++m)
#pragma unroll
        for (int n = 0; n < 4; ++n)
            acc[m][n] = (f32x4){0.f, 0.f, 0.f, 0.f};

    const int wr = (w >> 1) * 64;   // wave row offset in tile
    const int wc = (w & 1) * 64;    // wave col offset in tile
    const int rl = lane & 15;
    const int rh = lane >> 4;

    for (int k0 = 0; k0 < K; k0 += 64) {
#pragma unroll
        for (int r = 0; r < 4; ++r) {
            int idx8 = (r * 4 + w) * 64 + lane;       // 0..1023, each covers 8 bf16
            int row  = idx8 >> 3;                     // 0..127
            int col  = (idx8 & 7) * 8;                // 0..56
            gload_lds16(A + (size_t)(m0 + row) * K + k0 + col, As + idx8 * 8);
            gload_lds16(Bm + (size_t)(n0 + row) * K + k0 + col, Bs + idx8 * 8);
        }
        __syncthreads();
#pragma unroll
        for (int kk = 0; kk < 2; ++kk) {
            const int kof = kk * 32 + rh * 8;
            bf16x8 af[4], bfr[4];
#pragma unroll
            for (int m = 0; m < 4; ++m)
                af[m] = *(const bf16x8*)(As + (wr + m * 16 + rl) * 64 + kof);
#pragma unroll
            for (int n = 0; n < 4; ++n)
                bfr[n] = *(const bf16x8*)(Bs + (wc + n * 16 + rl) * 64 + kof);
#pragma unroll
            for (int m = 0; m < 4; ++m)
#pragma unroll
                for (int n = 0; n < 4; ++n)
                    acc[m][n] = __builtin_amdgcn_mfma_f32_16x16x32_bf16(af[m], bfr[n], acc[m][n], 0, 0, 0);
        }
        __syncthreads();
    }

    // epilogue: C/D layout col = lane&15, row = (lane>>4)*4 + reg; store bf16
#pragma unroll
    for (int m = 0; m < 4; ++m) {
#pragma unroll
        for (int n = 0; n < 4; ++n) {
            int gcol = n0 + wc + n * 16 + rl;
            float bv = bias[gcol];
#pragma unroll
            for (int j = 0; j < 4; ++j) {
                int grow = m0 + wr + m * 16 + rh * 4 + j;
                V[(size_t)grow * DIM + gcol] = f2bf(acc[m][n][j] + bv);
            }
        }
    }
}

// ---- pass A: per-chunk sums of v*cos, v*sin. 2 e-columns/thread ----
__global__ void passA_kernel(const unsigned short* __restrict__ val, const float* __restrict__ ph,
                             float* __restrict__ pr, float* __restrict__ pi) {
    int t  = blockIdx.x * 256 + threadIdx.x;      // 0..511 e-pair
    int c  = blockIdx.y;
    int bb = blockIdx.z;
    const ushort2* v = (const ushort2*)val + ((size_t)bb * SEQ + (size_t)c * CL) * (DIM / 2) + t;
    const float2*  p = (const float2*)ph + (size_t)c * CL * (DIM / 2) + t;
    float sr0 = 0.f, si0 = 0.f, sr1 = 0.f, si1 = 0.f;
    for (int l = 0; l < CL; ++l) {
        ushort2 vv = v[(size_t)l * (DIM / 2)];
        float2  pp = p[(size_t)l * (DIM / 2)];
        float v0 = bf2f(vv.x), v1 = bf2f(vv.y);
        float s0, c0, s1, c1;
        __sincosf(pp.x, &s0, &c0);
        __sincosf(pp.y, &s1, &c1);
        sr0 += v0 * c0; si0 += v0 * s0;
        sr1 += v1 * c1; si1 += v1 * s1;
    }
    size_t idx = ((size_t)bb * NC + c) * DIM + 2 * t;
    pr[idx] = sr0; pr[idx + 1] = sr1;
    pi[idx] = si0; pi[idx + 1] = si1;
}

// ---- pass B: exclusive scan of chunk partials over c ----
__global__ void passB_kernel(float* __restrict__ pr, float* __restrict__ pi) {
    int t = blockIdx.x * 256 + threadIdx.x;   // 0..4095
    int bb = t >> 10;
    int e  = t & 1023;
    float r = 0.f, im = 0.f;
    for (int c = 0; c < NC; ++c) {
        size_t idx = ((size_t)bb * NC + c) * DIM + e;
        float tr = pr[idx], ti = pi[idx];
        pr[idx] = r; pi[idx] = im;
        r += tr; im += ti;
    }
}

// ---- pass C: in-chunk running cumsum + retrieval + norm; reads bf16 value from ws,
//      writes fp32 to d_out (no aliasing) ----
__global__ void passC_kernel(const unsigned short* __restrict__ val, const float* __restrict__ ph,
                             const float* __restrict__ pr, const float* __restrict__ pi,
                             float* __restrict__ out) {
    int t  = blockIdx.x * 256 + threadIdx.x;      // 0..511 e-pair
    int c  = blockIdx.y;
    int bb = blockIdx.z;
    size_t base = ((size_t)bb * SEQ + (size_t)c * CL) * (DIM / 2) + t;
    const ushort2* v = (const ushort2*)val + base;
    const float2*  p = (const float2*)ph + (size_t)c * CL * (DIM / 2) + t;
    float2* o = (float2*)out + base;
    size_t pidx = ((size_t)bb * NC + c) * DIM + 2 * t;
    float ar0 = pr[pidx], ar1 = pr[pidx + 1];
    float ai0 = pi[pidx], ai1 = pi[pidx + 1];
    const int l0 = c * CL;
    for (int l = 0; l < CL; ++l) {
        ushort2 vv = v[(size_t)l * (DIM / 2)];
        float2  pp = p[(size_t)l * (DIM / 2)];
        float v0 = bf2f(vv.x), v1 = bf2f(vv.y);
        float s0, c0, s1, c1;
        __sincosf(pp.x, &s0, &c0);
        __sincosf(pp.y, &s1, &c1);
        ar0 += v0 * c0; ai0 += v0 * s0;
        ar1 += v1 * c1; ai1 += v1 * s1;
        float rn = rsqrtf((float)(l0 + l + 1));
        float2 ov;
        ov.x = (ar0 * c0 + ai0 * s0) * rn;
        ov.y = (ar1 * c1 + ai1 * s1) * rn;
        o[(size_t)l * (DIM / 2)] = ov;
    }
}

extern "C" void kernel_launch(void* const* d_in, const int* in_sizes, int n_in,
                              void* d_out, int out_size, void* d_ws, size_t ws_size,
                              hipStream_t stream) {
    const float* x  = (const float*)d_in[0];
    const float* ph = (const float*)d_in[1];   // base_phases [8192][1024]; first 4096 rows used
    const float* W  = (const float*)d_in[2];
    const float* b  = (const float*)d_in[3];
    float* out = (float*)d_out;

    // d_out doubles as scratch for the bf16 inputs until passC overwrites it:
    //   xb: [0, 32MiB)   wb: [32MiB, 34MiB)     (d_out is 64 MiB fp32)
    unsigned short* xb = (unsigned short*)d_out;
    unsigned short* wb = xb + (size_t)MROWS * DIM;

    // workspace: value bf16 [0,32MiB), pr [32,33MiB), pi [33,34MiB)
    unsigned short* vb = (unsigned short*)d_ws;
    float* pr = (float*)(vb + (size_t)MROWS * DIM);
    float* pi = pr + (size_t)NB * NC * DIM;

    // 1) convert x, W to bf16 (into d_out scratch region)
    {
        long long total4 = (long long)MROWS * DIM / 4 + (long long)DIM * DIM / 4;
        int blocks = (int)((total4 + 255) / 256);
        convert_kernel<<<blocks, 256, 0, stream>>>(x, W, xb, wb);
    }
    // 2) GEMM -> bf16 value into ws
    {
        dim3 grid(MROWS / 128, DIM / 128);
        gemm_kernel<<<grid, 256, 0, stream>>>(xb, wb, b, vb);
    }
    // 3) chunk partial sums
    {
        dim3 grid(DIM / 512, NC, NB);
        passA_kernel<<<grid, 256, 0, stream>>>(vb, ph, pr, pi);
    }
    // 4) scan partials
    passB_kernel<<<16, 256, 0, stream>>>(pr, pi);
    // 5) final cumsum + retrieve + norm -> fp32 d_out
    {
        dim3 grid(DIM / 512, NC, NB);
        passC_kernel<<<grid, 256, 0, stream>>>(vb, ph, pr, pi, out);
    }
}

// Round 3
// 93.687 us; speedup vs baseline: 1.6103x; 1.1999x over previous
//
#include <hip/hip_runtime.h>
#include <hip/hip_bf16.h>

#define DIM 1024
#define SEQ 4096
#define NB 4
#define MROWS (NB * SEQ)   // 16384
#define NC 64              // chunks per sequence
#define CL (SEQ / NC)      // 64 L-positions per chunk

// GEMM tiling
#define BM 256
#define BN 256
#define BK 32
#define NT (DIM / BK)      // 32 K-tiles
#define TILE_LDS 32768     // A half (16KB) + B half (16KB) per K-tile
#define GEMM_LDS (4 * TILE_LDS)   // 128 KiB, 4-buffer rotation

typedef __attribute__((ext_vector_type(8))) short bf16x8;
typedef __attribute__((ext_vector_type(4))) float f32x4;

static __device__ __forceinline__ unsigned short f2bf(float f) {
    union { float f; unsigned u; } v; v.f = f;
    unsigned r = v.u + 0x7FFF + ((v.u >> 16) & 1);
    return (unsigned short)(r >> 16);
}

static __device__ __forceinline__ float bf2f(unsigned short h) {
    union { unsigned u; float f; } v; v.u = ((unsigned)h) << 16;
    return v.f;
}

static __device__ __forceinline__ void gload_lds16(const void* g, void* l) {
    __builtin_amdgcn_global_load_lds((const __attribute__((address_space(1))) void*)g,
                                     (__attribute__((address_space(3))) void*)l, 16, 0, 0);
}

// ---- convert x and W fp32 -> bf16 ----
__global__ void convert_kernel(const float* __restrict__ x, const float* __restrict__ W,
                               unsigned short* __restrict__ xb, unsigned short* __restrict__ wb) {
    const long long NX4 = (long long)MROWS * DIM / 4;
    const long long NW4 = (long long)DIM * DIM / 4;
    long long t = (long long)blockIdx.x * blockDim.x + threadIdx.x;
    if (t < NX4) {
        float4 v = ((const float4*)x)[t];
        ushort4 o;
        o.x = f2bf(v.x); o.y = f2bf(v.y); o.z = f2bf(v.z); o.w = f2bf(v.w);
        ((ushort4*)xb)[t] = o;
    } else if (t < NX4 + NW4) {
        long long u = t - NX4;
        float4 v = ((const float4*)W)[u];
        ushort4 o;
        o.x = f2bf(v.x); o.y = f2bf(v.y); o.z = f2bf(v.z); o.w = f2bf(v.w);
        ((ushort4*)wb)[u] = o;
    }
}

// Stage one K-tile half (A or B) of tile s into buffer q.
// LDS linear [256 rows][64 B]; global source pre-swizzled: LDS slot s16 holds
// global 16B-chunk c16 = s16 ^ (row & 3)  (involution; undone on ds_read).
static __device__ __forceinline__ void stage_A(const unsigned short* __restrict__ A, char* smem,
                                               int q, int m0, int ks, int w, int lane) {
#pragma unroll
    for (int r = 0; r < 2; ++r) {
        int row  = r * 128 + w * 16 + (lane >> 2);
        int c16  = (lane & 3) ^ (row & 3);
        const unsigned short* g = A + (size_t)(m0 + row) * DIM + ks + c16 * 8;
        char* l = smem + q * TILE_LDS + (r * 128 + w * 16) * 64 + lane * 16;
        gload_lds16(g, l);
    }
}

static __device__ __forceinline__ void stage_B(const unsigned short* __restrict__ Bm, char* smem,
                                               int q, int n0, int ks, int w, int lane) {
#pragma unroll
    for (int r = 0; r < 2; ++r) {
        int row  = r * 128 + w * 16 + (lane >> 2);
        int c16  = (lane & 3) ^ (row & 3);
        const unsigned short* g = Bm + (size_t)(n0 + row) * DIM + ks + c16 * 8;
        char* l = smem + q * TILE_LDS + 16384 + (r * 128 + w * 16) * 64 + lane * 16;
        gload_lds16(g, l);
    }
}

// ---- GEMM: V[m][n] = bf16( sum_k A[m][k]*B[n][k] + bias[n] ) ----
// 256x256 tile, BK=32, 4-deep LDS rotation, counted vmcnt(8), 8 waves (2Mx4N).
__global__ __launch_bounds__(512, 2) void gemm_kernel(const unsigned short* __restrict__ A,
                                                      const unsigned short* __restrict__ Bm,
                                                      const float* __restrict__ bias,
                                                      unsigned short* __restrict__ V) {
    extern __shared__ char smem[];
    const int tid  = threadIdx.x;
    const int lane = tid & 63;
    const int w    = tid >> 6;           // wave 0..7
    const int wm   = w >> 2;             // 0..1
    const int wn   = w & 3;              // 0..3
    const int wr   = wm * 128;           // wave row offset (M)
    const int wc   = wn * 64;            // wave col offset (N)
    const int rl   = lane & 15;
    const int rh   = lane >> 4;
    const int swz  = ((rh ^ (rl & 3)) * 16);   // swizzled 16B slot within 64B row
    const int m0   = blockIdx.x * BM;
    const int n0   = blockIdx.y * BN;

    f32x4 acc[8][4];
#pragma unroll
    for (int m = 0; m < 8; ++m)
#pragma unroll
        for (int n = 0; n < 4; ++n)
            acc[m][n] = (f32x4){0.f, 0.f, 0.f, 0.f};

    // prologue: stage tiles 0,1,2 (12 loads/thread in flight)
#pragma unroll
    for (int s = 0; s < 3; ++s) {
        stage_A(A, smem, s, m0, s * BK, w, lane);
        stage_B(Bm, smem, s, n0, s * BK, w, lane);
    }

#pragma unroll 4
    for (int t = 0; t < NT; ++t) {
        const int q = t & 3;
        // oldest 4 loads (tile t's A+B) must have landed; keep 8 in flight
        asm volatile("s_waitcnt vmcnt(8)" ::: "memory");
        __builtin_amdgcn_s_barrier();

        const int snext = t + 3;
        const int qn = snext & 3;
        const int ksn = (snext & (NT - 1)) * BK;   // wraps harmlessly into dead buffers at tail
        char* base = smem + q * TILE_LDS;

        // ---- phase A: m-frags 0..3 x n-frags 0..3 ----
        bf16x8 bfr[4];
#pragma unroll
        for (int nf = 0; nf < 4; ++nf)
            bfr[nf] = *(const bf16x8*)(base + 16384 + (wc + nf * 16 + rl) * 64 + swz);
        bf16x8 af[4];
#pragma unroll
        for (int mf = 0; mf < 4; ++mf)
            af[mf] = *(const bf16x8*)(base + (wr + mf * 16 + rl) * 64 + swz);
        stage_A(A, smem, qn, m0, ksn, w, lane);
        __builtin_amdgcn_s_setprio(1);
#pragma unroll
        for (int mf = 0; mf < 4; ++mf)
#pragma unroll
            for (int nf = 0; nf < 4; ++nf)
                acc[mf][nf] = __builtin_amdgcn_mfma_f32_16x16x32_bf16(af[mf], bfr[nf], acc[mf][nf], 0, 0, 0);
        __builtin_amdgcn_s_setprio(0);

        // ---- phase B: m-frags 4..7 x n-frags 0..3 (B frags reused) ----
#pragma unroll
        for (int mf = 0; mf < 4; ++mf)
            af[mf] = *(const bf16x8*)(base + (wr + (mf + 4) * 16 + rl) * 64 + swz);
        stage_B(Bm, smem, qn, n0, ksn, w, lane);
        __builtin_amdgcn_s_setprio(1);
#pragma unroll
        for (int mf = 0; mf < 4; ++mf)
#pragma unroll
            for (int nf = 0; nf < 4; ++nf)
                acc[mf + 4][nf] = __builtin_amdgcn_mfma_f32_16x16x32_bf16(af[mf], bfr[nf], acc[mf + 4][nf], 0, 0, 0);
        __builtin_amdgcn_s_setprio(0);
    }

    // epilogue: C/D layout col = lane&15, row = (lane>>4)*4 + reg; store bf16
#pragma unroll
    for (int mf = 0; mf < 8; ++mf) {
#pragma unroll
        for (int nf = 0; nf < 4; ++nf) {
            int gcol = n0 + wc + nf * 16 + rl;
            float bv = bias[gcol];
#pragma unroll
            for (int j = 0; j < 4; ++j) {
                int grow = m0 + wr + mf * 16 + rh * 4 + j;
                V[(size_t)grow * DIM + gcol] = f2bf(acc[mf][nf][j] + bv);
            }
        }
    }
}

// ---- pass A: per-chunk sums of v*cos, v*sin. 2 e-columns/thread ----
__global__ void passA_kernel(const unsigned short* __restrict__ val, const float* __restrict__ ph,
                             float* __restrict__ pr, float* __restrict__ pi) {
    int t  = blockIdx.x * 256 + threadIdx.x;
    int c  = blockIdx.y;
    int bb = blockIdx.z;
    const ushort2* v = (const ushort2*)val + ((size_t)bb * SEQ + (size_t)c * CL) * (DIM / 2) + t;
    const float2*  p = (const float2*)ph + (size_t)c * CL * (DIM / 2) + t;
    float sr0 = 0.f, si0 = 0.f, sr1 = 0.f, si1 = 0.f;
    for (int l = 0; l < CL; ++l) {
        ushort2 vv = v[(size_t)l * (DIM / 2)];
        float2  pp = p[(size_t)l * (DIM / 2)];
        float v0 = bf2f(vv.x), v1 = bf2f(vv.y);
        float s0, c0, s1, c1;
        __sincosf(pp.x, &s0, &c0);
        __sincosf(pp.y, &s1, &c1);
        sr0 += v0 * c0; si0 += v0 * s0;
        sr1 += v1 * c1; si1 += v1 * s1;
    }
    size_t idx = ((size_t)bb * NC + c) * DIM + 2 * t;
    pr[idx] = sr0; pr[idx + 1] = sr1;
    pi[idx] = si0; pi[idx + 1] = si1;
}

// ---- pass B: exclusive scan of chunk partials over c ----
__global__ void passB_kernel(float* __restrict__ pr, float* __restrict__ pi) {
    int t = blockIdx.x * 256 + threadIdx.x;
    int bb = t >> 10;
    int e  = t & 1023;
    float r = 0.f, im = 0.f;
    for (int c = 0; c < NC; ++c) {
        size_t idx = ((size_t)bb * NC + c) * DIM + e;
        float tr = pr[idx], ti = pi[idx];
        pr[idx] = r; pi[idx] = im;
        r += tr; im += ti;
    }
}

// ---- pass C: running cumsum + retrieval + norm -> fp32 out ----
__global__ void passC_kernel(const unsigned short* __restrict__ val, const float* __restrict__ ph,
                             const float* __restrict__ pr, const float* __restrict__ pi,
                             float* __restrict__ out) {
    int t  = blockIdx.x * 256 + threadIdx.x;
    int c  = blockIdx.y;
    int bb = blockIdx.z;
    size_t base = ((size_t)bb * SEQ + (size_t)c * CL) * (DIM / 2) + t;
    const ushort2* v = (const ushort2*)val + base;
    const float2*  p = (const float2*)ph + (size_t)c * CL * (DIM / 2) + t;
    float2* o = (float2*)out + base;
    size_t pidx = ((size_t)bb * NC + c) * DIM + 2 * t;
    float ar0 = pr[pidx], ar1 = pr[pidx + 1];
    float ai0 = pi[pidx], ai1 = pi[pidx + 1];
    const int l0 = c * CL;
    for (int l = 0; l < CL; ++l) {
        ushort2 vv = v[(size_t)l * (DIM / 2)];
        float2  pp = p[(size_t)l * (DIM / 2)];
        float v0 = bf2f(vv.x), v1 = bf2f(vv.y);
        float s0, c0, s1, c1;
        __sincosf(pp.x, &s0, &c0);
        __sincosf(pp.y, &s1, &c1);
        ar0 += v0 * c0; ai0 += v0 * s0;
        ar1 += v1 * c1; ai1 += v1 * s1;
        float rn = rsqrtf((float)(l0 + l + 1));
        float2 ov;
        ov.x = (ar0 * c0 + ai0 * s0) * rn;
        ov.y = (ar1 * c1 + ai1 * s1) * rn;
        o[(size_t)l * (DIM / 2)] = ov;
    }
}

extern "C" void kernel_launch(void* const* d_in, const int* in_sizes, int n_in,
                              void* d_out, int out_size, void* d_ws, size_t ws_size,
                              hipStream_t stream) {
    const float* x  = (const float*)d_in[0];
    const float* ph = (const float*)d_in[1];
    const float* W  = (const float*)d_in[2];
    const float* b  = (const float*)d_in[3];
    float* out = (float*)d_out;

    // d_out doubles as scratch for bf16 inputs until passC overwrites it
    unsigned short* xb = (unsigned short*)d_out;
    unsigned short* wb = xb + (size_t)MROWS * DIM;

    // ws: value bf16 [0,32MiB), pr, pi
    unsigned short* vb = (unsigned short*)d_ws;
    float* pr = (float*)(vb + (size_t)MROWS * DIM);
    float* pi = pr + (size_t)NB * NC * DIM;

    // allow 128 KiB dynamic LDS for the GEMM (no-op if already allowed)
    (void)hipFuncSetAttribute((const void*)gemm_kernel,
                              hipFuncAttributeMaxDynamicSharedMemorySize, GEMM_LDS);

    // 1) convert
    {
        long long total4 = (long long)MROWS * DIM / 4 + (long long)DIM * DIM / 4;
        int blocks = (int)((total4 + 255) / 256);
        convert_kernel<<<blocks, 256, 0, stream>>>(x, W, xb, wb);
    }
    // 2) GEMM -> bf16 value into ws
    {
        dim3 grid(MROWS / BM, DIM / BN);
        gemm_kernel<<<grid, 512, GEMM_LDS, stream>>>(xb, wb, b, vb);
    }
    // 3) chunk partial sums
    {
        dim3 grid(DIM / 512, NC, NB);
        passA_kernel<<<grid, 256, 0, stream>>>(vb, ph, pr, pi);
    }
    // 4) scan partials
    passB_kernel<<<16, 256, 0, stream>>>(pr, pi);
    // 5) final cumsum + retrieve + norm -> fp32 d_out
    {
        dim3 grid(DIM / 512, NC, NB);
        passC_kernel<<<grid, 256, 0, stream>>>(vb, ph, pr, pi, out);
    }
}